// Round 8
// baseline (87.819 us; speedup 1.0000x reference)
//
#include <hip/hip_runtime.h>
#include <stdint.h>

// ANFM: B=4096, F=26, V=20000, E=64, P=325 pairs.
// k1: 4 samples/block (256 thr), ONE WAVE PER SAMPLE, single barrier.
//     FUSED phase 2: per tile, MFMA scores -> exp (max-free: softmax is
//     shift-invariant and scores are O(0.1), no overflow) -> online-weighted
//     accumulation of the SAME af pair-product fragments into acf[16] via
//     fma_mix. Phases 3/4 and scoresL deleted. One c16-butterfly finishes.
// k2: MLP head 64->256->128->1 (+lr+bias), 8 samples/block.
#define B_N 4096
#define F_N 26
#define V_N 20000
#define E_N 64
#define P_N 325
#define PT  21   // ceil(336/16) pair M-tiles (padded to 336 rows)

typedef __attribute__((ext_vector_type(8))) _Float16 half8;
typedef __attribute__((ext_vector_type(4))) _Float16 half4;
typedef __attribute__((ext_vector_type(4))) float floatx4;

// ---------------- attention kernel: 4 samples/block, 1 wave/sample --------
__global__ __launch_bounds__(256, 4) void anfm_attn_kernel(
    const int* __restrict__ x_idx, const float* __restrict__ embed_w,
    const float* __restrict__ embed_b, const float* __restrict__ att_w,
    const float* __restrict__ att_b, const float* __restrict__ att_p,
    float* __restrict__ ws_afm, float* __restrict__ ws_lr)
{
    __shared__ _Float16 xwb[4][F_N][72];   // fp16 gathered embeds (pad 72)
    __shared__ _Float16 WT[64][72];        // W^T fp16: WT[col][k] (pad 72)
    __shared__ unsigned short pijL[336];   // (i<<8)|j per pair
    __shared__ int   sIdx[4][F_N];
    __shared__ float lrbuf[4][F_N];

    const int tid  = threadIdx.x;
    const int lane = tid & 63;
    const int wid  = tid >> 6;
    const int c16  = lane & 15;
    const int g    = lane >> 4;
    const int b    = blockIdx.x * 4 + wid;   // sample owned by this wave

    // ---- phase 0 (cooperative): indices, lr gather, pair map, W^T stage ----
    if (tid < 4 * F_N) {
        int s = tid / F_N, f = tid - s * F_N;
        int idx = x_idx[(blockIdx.x * 4 + s) * F_N + f];
        sIdx[s][f]  = idx;
        lrbuf[s][f] = embed_b[f * V_N + idx];
    }
    for (int p = tid; p < 336; p += 256) {
        int i = 0, j = 1;
        if (p < P_N) {
            i = (int)((51.0f - sqrtf(2601.0f - 8.0f * (float)p)) * 0.5f);
            if (i * (51 - i) / 2 > p) i--;
            else if ((i + 1) * (50 - i) / 2 <= p) i++;
            j = p - i * (51 - i) / 2 + i + 1;
        }
        pijL[p] = (unsigned short)((i << 8) | j);
    }
    // W^T staging: WT[col][k] = att_w[k][col]  (coalesced f32 read)
    for (int idx = tid; idx < 64 * 64; idx += 256) {
        int k = idx >> 6, col = idx & 63;
        WT[col][k] = (_Float16)att_w[idx];
    }
    // per-lane attention p / bias for hidden units n = nt*16 + g*4 + r (L2 reads)
    float apr[16], abr[16];
    #pragma unroll
    for (int nt = 0; nt < 4; nt++)
        #pragma unroll
        for (int r = 0; r < 4; r++) {
            apr[nt * 4 + r] = att_p[nt * 16 + g * 4 + r];
            abr[nt * 4 + r] = att_b[nt * 16 + g * 4 + r];
        }
    __syncthreads();   // the ONLY block-wide barrier

    // W fragments (rows of W^T) in registers; k-slot (g,u) <-> k = s*32+8g+u
    half8 bfr[4][2];
    #pragma unroll
    for (int nt = 0; nt < 4; nt++)
        #pragma unroll
        for (int s = 0; s < 2; s++)
            bfr[nt][s] = *reinterpret_cast<const half8*>(
                &WT[nt * 16 + c16][s * 32 + g * 8]);

    // ---- phase 1 (wave-local): gather own sample's embeddings ----
    #pragma unroll
    for (int it = 0; it < 7; it++) {
        int f = it * 4 + g;
        if (f < F_N) {
            const float4* src = reinterpret_cast<const float4*>(
                embed_w + ((size_t)(f * V_N + sIdx[wid][f])) * E_N);
            float4 v = src[c16];
            half4 hv = {(_Float16)v.x, (_Float16)v.y, (_Float16)v.z, (_Float16)v.w};
            *reinterpret_cast<half4*>(&xwb[wid][f][c16 * 4]) = hv;
        }
    }

    // ---- phase 2 (wave-local, FUSED): MFMA scores -> exp -> weighted acc ----
    // D = W^T(A) @ pairs^T(B): D col = lane&15 = pair, row = g*4+r = hidden n.
    // After the two cross-g shuffles every lane holds the FULL score of pair
    // c16 in this tile -> per-lane w = exp(score) weights the af fragments
    // this lane already owns (e = s*32 + 8g + u).  Max-free exp is exact up
    // to softmax shift-invariance; scores are O(0.1) here so no overflow.
    float acf[16];
    #pragma unroll
    for (int u = 0; u < 16; u++) acf[u] = 0.f;
    float Zp = 0.f;

    #pragma unroll 2
    for (int t = 0; t < PT; t++) {
        int pk = pijL[t * 16 + c16];
        int ri = pk >> 8, rj = pk & 255;
        half8 af[2];
        #pragma unroll
        for (int s = 0; s < 2; s++) {
            half8 xv = *reinterpret_cast<const half8*>(&xwb[wid][ri][s * 32 + g * 8]);
            half8 yv = *reinterpret_cast<const half8*>(&xwb[wid][rj][s * 32 + g * 8]);
            af[s] = xv * yv;   // 4x v_pk_mul_f16
        }
        float scq = 0.f;
        #pragma unroll
        for (int nt = 0; nt < 4; nt++) {
            floatx4 acc = {abr[nt * 4 + 0], abr[nt * 4 + 1],
                           abr[nt * 4 + 2], abr[nt * 4 + 3]};
            acc = __builtin_amdgcn_mfma_f32_16x16x32_f16(bfr[nt][0], af[0], acc, 0, 0, 0);
            acc = __builtin_amdgcn_mfma_f32_16x16x32_f16(bfr[nt][1], af[1], acc, 0, 0, 0);
            #pragma unroll
            for (int r = 0; r < 4; r++)
                scq = fmaf(apr[nt * 4 + r], fmaxf(acc[r], 0.f), scq);
        }
        scq += __shfl_xor(scq, 16);   // reduce over g groups (hidden chunks)
        scq += __shfl_xor(scq, 32);
        float w = (t * 16 + c16 < P_N) ? __expf(scq) : 0.f;
        Zp += w;
        #pragma unroll
        for (int s = 0; s < 2; s++)
            #pragma unroll
            for (int u = 0; u < 8; u++)
                acf[s * 8 + u] = fmaf((float)af[s][u], w, acf[s * 8 + u]);  // fma_mix
    }

    // ---- reduce over the 16 pair-columns (c16) within each g-group ----
    #pragma unroll
    for (int msk = 1; msk <= 8; msk <<= 1) {
        Zp += __shfl_xor(Zp, msk);
        #pragma unroll
        for (int u = 0; u < 16; u++) acf[u] += __shfl_xor(acf[u], msk);
    }

    // ---- write afm (lanes c16==0: g picks the 8-element e-chunks) + lr ----
    if (c16 == 0) {
        float rZ = 1.f / Zp;
        #pragma unroll
        for (int s = 0; s < 2; s++) {
            floatx4 o0 = {acf[s * 8 + 0] * rZ, acf[s * 8 + 1] * rZ,
                          acf[s * 8 + 2] * rZ, acf[s * 8 + 3] * rZ};
            floatx4 o1 = {acf[s * 8 + 4] * rZ, acf[s * 8 + 5] * rZ,
                          acf[s * 8 + 6] * rZ, acf[s * 8 + 7] * rZ};
            *reinterpret_cast<floatx4*>(&ws_afm[(size_t)b * 64 + s * 32 + g * 8])     = o0;
            *reinterpret_cast<floatx4*>(&ws_afm[(size_t)b * 64 + s * 32 + g * 8 + 4]) = o1;
        }
    }
    float lv = (lane < F_N) ? lrbuf[wid][lane] : 0.f;
    #pragma unroll
    for (int off = 32; off; off >>= 1) lv += __shfl_xor(lv, off);
    if (lane == 0) ws_lr[b] = lv;
}

// ---------------- MLP head: 8 samples per block ----------------
__global__ __launch_bounds__(256, 4) void anfm_mlp_kernel(
    const float* __restrict__ ws_afm, const float* __restrict__ ws_lr,
    const float* __restrict__ w0, const float* __restrict__ b0,
    const float* __restrict__ w1, const float* __restrict__ b1,
    const float* __restrict__ w2, const float* __restrict__ b2,
    const float* __restrict__ bias, float* __restrict__ out)
{
    __shared__ float afm_t[8][64];
    __shared__ float h0t[8][256];
    const int tid  = threadIdx.x;
    const int lane = tid & 63;
    const int w    = tid >> 6;
    const int blk  = blockIdx.x;
    const int s0   = w * 2;    // this wave's first local sample

    for (int it = tid; it < 8 * 64; it += 256) {
        int s = it >> 6, e = it & 63;
        afm_t[s][e] = ws_afm[((size_t)blk * 8 + s) * 64 + e];
    }
    __syncthreads();

    // L0: 64 -> 256
    float acc0[2][4];
    float bb0[4];
    #pragma unroll
    for (int q = 0; q < 4; q++) bb0[q] = b0[lane + 64 * q];
    #pragma unroll
    for (int s = 0; s < 2; s++)
        #pragma unroll
        for (int q = 0; q < 4; q++) acc0[s][q] = bb0[q];
    for (int e = 0; e < 64; e += 4) {
        floatx4 a[2];
        #pragma unroll
        for (int s = 0; s < 2; s++)
            a[s] = *reinterpret_cast<const floatx4*>(&afm_t[s0 + s][e]);
        #pragma unroll
        for (int k = 0; k < 4; k++) {
            float wv[4];
            #pragma unroll
            for (int q = 0; q < 4; q++) wv[q] = w0[(e + k) * 256 + lane + 64 * q];
            #pragma unroll
            for (int s = 0; s < 2; s++)
                #pragma unroll
                for (int q = 0; q < 4; q++)
                    acc0[s][q] = fmaf(a[s][k], wv[q], acc0[s][q]);
        }
    }
    #pragma unroll
    for (int s = 0; s < 2; s++)
        #pragma unroll
        for (int q = 0; q < 4; q++)
            h0t[s0 + s][lane + 64 * q] = fmaxf(acc0[s][q], 0.f);
    __syncthreads();

    // L1: 256 -> 128
    float acc1[2][2];
    float bb1[2];
    #pragma unroll
    for (int q = 0; q < 2; q++) bb1[q] = b1[lane + 64 * q];
    #pragma unroll
    for (int s = 0; s < 2; s++)
        #pragma unroll
        for (int q = 0; q < 2; q++) acc1[s][q] = bb1[q];
    for (int e = 0; e < 256; e += 4) {
        floatx4 h[2];
        #pragma unroll
        for (int s = 0; s < 2; s++)
            h[s] = *reinterpret_cast<const floatx4*>(&h0t[s0 + s][e]);
        #pragma unroll
        for (int k = 0; k < 4; k++) {
            float wv[2];
            #pragma unroll
            for (int q = 0; q < 2; q++) wv[q] = w1[(e + k) * 128 + lane + 64 * q];
            #pragma unroll
            for (int s = 0; s < 2; s++)
                #pragma unroll
                for (int q = 0; q < 2; q++)
                    acc1[s][q] = fmaf(h[s][k], wv[q], acc1[s][q]);
        }
    }

    // L2: 128 -> 1, + lr + bias
    float w2a = w2[lane], w2b = w2[lane + 64];
    float base = b2[0] + bias[0];
    #pragma unroll
    for (int s = 0; s < 2; s++) {
        float part = fmaxf(acc1[s][0], 0.f) * w2a + fmaxf(acc1[s][1], 0.f) * w2b;
        #pragma unroll
        for (int off = 32; off; off >>= 1) part += __shfl_xor(part, off);
        if (lane == 0) {
            int sg = blk * 8 + s0 + s;
            out[sg] = part + base + ws_lr[sg];
        }
    }
}

extern "C" void kernel_launch(void* const* d_in, const int* in_sizes, int n_in,
                              void* d_out, int out_size, void* d_ws, size_t ws_size,
                              hipStream_t stream) {
    const int*   x_idx   = (const int*)d_in[0];
    const float* embed_w = (const float*)d_in[1];
    const float* embed_b = (const float*)d_in[2];
    const float* att_w   = (const float*)d_in[3];
    const float* att_b   = (const float*)d_in[4];
    const float* att_p   = (const float*)d_in[5];
    const float* w0      = (const float*)d_in[6];
    const float* b0      = (const float*)d_in[7];
    const float* w1      = (const float*)d_in[8];
    const float* b1      = (const float*)d_in[9];
    const float* w2      = (const float*)d_in[10];
    const float* b2      = (const float*)d_in[11];
    const float* bias    = (const float*)d_in[12];

    // ws layout: afm [B,64] f32 | lr [B] f32
    float* ws_afm = (float*)d_ws;
    float* ws_lr  = ws_afm + (size_t)B_N * E_N;
    float* out    = (float*)d_out;

    anfm_attn_kernel<<<B_N / 4, 256, 0, stream>>>(x_idx, embed_w, embed_b,
                                                  att_w, att_b, att_p,
                                                  ws_afm, ws_lr);
    anfm_mlp_kernel<<<B_N / 8, 256, 0, stream>>>(ws_afm, ws_lr,
                                                 w0, b0, w1, b1, w2, b2, bias, out);
}

// Round 9
// 47.809 us; speedup vs baseline: 1.8369x; 1.8369x over previous
//
#include <hip/hip_runtime.h>
#include <stdint.h>

// ANFM: B=4096, F=26, V=20000, E=64, P=325 pairs.
// k1: 4 samples/block (256 thr), ONE WAVE PER SAMPLE, single barrier.
//     FUSED phase 2 (validated round 8): MFMA scores -> max-free exp ->
//     online-weighted accumulation of the SAME af fragments into acf[16].
//     Round-9 fix: ap/ab read from LDS per tile (frees 32 VGPRs) and
//     unroll 1 -> live set ~86 < 128 cap -> NO SPILL (round-8 failure).
// k2: MLP head 64->256->128->1 (+lr+bias), 8 samples/block.
#define B_N 4096
#define F_N 26
#define V_N 20000
#define E_N 64
#define P_N 325
#define PT  21   // ceil(336/16) pair M-tiles (padded to 336 rows)

typedef __attribute__((ext_vector_type(8))) _Float16 half8;
typedef __attribute__((ext_vector_type(4))) _Float16 half4;
typedef __attribute__((ext_vector_type(4))) float floatx4;

// ---------------- attention kernel: 4 samples/block, 1 wave/sample --------
__global__ __launch_bounds__(256, 4) void anfm_attn_kernel(
    const int* __restrict__ x_idx, const float* __restrict__ embed_w,
    const float* __restrict__ embed_b, const float* __restrict__ att_w,
    const float* __restrict__ att_b, const float* __restrict__ att_p,
    float* __restrict__ ws_afm, float* __restrict__ ws_lr)
{
    __shared__ _Float16 xwb[4][F_N][72];   // fp16 gathered embeds (pad 72)
    __shared__ _Float16 WT[64][72];        // W^T fp16: WT[col][k] (pad 72)
    __shared__ unsigned short pijL[336];   // (i<<8)|j per pair
    __shared__ int   sIdx[4][F_N];
    __shared__ float lrbuf[4][F_N];
    __shared__ float apL[64], abL[64];     // attention_p / attention_b

    const int tid  = threadIdx.x;
    const int lane = tid & 63;
    const int wid  = tid >> 6;
    const int c16  = lane & 15;
    const int g    = lane >> 4;
    const int b    = blockIdx.x * 4 + wid;   // sample owned by this wave

    // ---- phase 0 (cooperative): indices, lr, pair map, W^T, ap/ab stage ----
    if (tid < 4 * F_N) {
        int s = tid / F_N, f = tid - s * F_N;
        int idx = x_idx[(blockIdx.x * 4 + s) * F_N + f];
        sIdx[s][f]  = idx;
        lrbuf[s][f] = embed_b[f * V_N + idx];
    }
    for (int p = tid; p < 336; p += 256) {
        int i = 0, j = 1;
        if (p < P_N) {
            i = (int)((51.0f - sqrtf(2601.0f - 8.0f * (float)p)) * 0.5f);
            if (i * (51 - i) / 2 > p) i--;
            else if ((i + 1) * (50 - i) / 2 <= p) i++;
            j = p - i * (51 - i) / 2 + i + 1;
        }
        pijL[p] = (unsigned short)((i << 8) | j);
    }
    if (tid < 64)                   apL[tid]      = att_p[tid];
    else if (tid < 128)             abL[tid - 64] = att_b[tid - 64];
    // W^T staging: WT[col][k] = att_w[k][col]  (coalesced f32 read)
    for (int idx = tid; idx < 64 * 64; idx += 256) {
        int k = idx >> 6, col = idx & 63;
        WT[col][k] = (_Float16)att_w[idx];
    }
    __syncthreads();   // the ONLY block-wide barrier

    // W fragments (rows of W^T) in registers; k-slot (g,u) <-> k = s*32+8g+u
    half8 bfr[4][2];
    #pragma unroll
    for (int nt = 0; nt < 4; nt++)
        #pragma unroll
        for (int s = 0; s < 2; s++)
            bfr[nt][s] = *reinterpret_cast<const half8*>(
                &WT[nt * 16 + c16][s * 32 + g * 8]);

    // ---- phase 1 (wave-local): gather own sample's embeddings ----
    #pragma unroll
    for (int it = 0; it < 7; it++) {
        int f = it * 4 + g;
        if (f < F_N) {
            const float4* src = reinterpret_cast<const float4*>(
                embed_w + ((size_t)(f * V_N + sIdx[wid][f])) * E_N);
            float4 v = src[c16];
            half4 hv = {(_Float16)v.x, (_Float16)v.y, (_Float16)v.z, (_Float16)v.w};
            *reinterpret_cast<half4*>(&xwb[wid][f][c16 * 4]) = hv;
        }
    }

    // ---- phase 2 (wave-local, FUSED): MFMA scores -> exp -> weighted acc ----
    // D = W^T(A) @ pairs^T(B): D col = lane&15 = pair, row = g*4+r = hidden n.
    // After the cross-g shuffles every lane holds the FULL score of pair c16
    // in this tile -> per-lane w = exp(score) weights the af fragments this
    // lane already owns (e = s*32 + 8g + u). Max-free exp: softmax is
    // shift-invariant and scores are O(0.1) -> no overflow. ab via the MFMA
    // C operand (LDS broadcast), ap via LDS broadcast -> no apr/abr arrays.
    float acf[16];
    #pragma unroll
    for (int u = 0; u < 16; u++) acf[u] = 0.f;
    float Zp = 0.f;

    #pragma unroll 1
    for (int t = 0; t < PT; t++) {
        int pk = pijL[t * 16 + c16];
        int ri = pk >> 8, rj = pk & 255;
        half8 af[2];
        #pragma unroll
        for (int s = 0; s < 2; s++) {
            half8 xv = *reinterpret_cast<const half8*>(&xwb[wid][ri][s * 32 + g * 8]);
            half8 yv = *reinterpret_cast<const half8*>(&xwb[wid][rj][s * 32 + g * 8]);
            af[s] = xv * yv;   // 4x v_pk_mul_f16
        }
        float scq = 0.f;
        #pragma unroll
        for (int nt = 0; nt < 4; nt++) {
            floatx4 acc = *reinterpret_cast<const floatx4*>(&abL[nt * 16 + g * 4]);
            acc = __builtin_amdgcn_mfma_f32_16x16x32_f16(bfr[nt][0], af[0], acc, 0, 0, 0);
            acc = __builtin_amdgcn_mfma_f32_16x16x32_f16(bfr[nt][1], af[1], acc, 0, 0, 0);
            floatx4 ap4 = *reinterpret_cast<const floatx4*>(&apL[nt * 16 + g * 4]);
            #pragma unroll
            for (int r = 0; r < 4; r++)
                scq = fmaf(ap4[r], fmaxf(acc[r], 0.f), scq);
        }
        scq += __shfl_xor(scq, 16);   // reduce over g groups (hidden chunks)
        scq += __shfl_xor(scq, 32);
        float w = (t * 16 + c16 < P_N) ? __expf(scq) : 0.f;
        Zp += w;
        #pragma unroll
        for (int s = 0; s < 2; s++)
            #pragma unroll
            for (int u = 0; u < 8; u++)
                acf[s * 8 + u] = fmaf((float)af[s][u], w, acf[s * 8 + u]);  // fma_mix
    }

    // ---- reduce over the 16 pair-columns (c16) within each g-group ----
    #pragma unroll
    for (int msk = 1; msk <= 8; msk <<= 1) {
        Zp += __shfl_xor(Zp, msk);
        #pragma unroll
        for (int u = 0; u < 16; u++) acf[u] += __shfl_xor(acf[u], msk);
    }

    // ---- write afm (lanes c16==0: g picks the 8-element e-chunks) + lr ----
    if (c16 == 0) {
        float rZ = 1.f / Zp;
        #pragma unroll
        for (int s = 0; s < 2; s++) {
            floatx4 o0 = {acf[s * 8 + 0] * rZ, acf[s * 8 + 1] * rZ,
                          acf[s * 8 + 2] * rZ, acf[s * 8 + 3] * rZ};
            floatx4 o1 = {acf[s * 8 + 4] * rZ, acf[s * 8 + 5] * rZ,
                          acf[s * 8 + 6] * rZ, acf[s * 8 + 7] * rZ};
            *reinterpret_cast<floatx4*>(&ws_afm[(size_t)b * 64 + s * 32 + g * 8])     = o0;
            *reinterpret_cast<floatx4*>(&ws_afm[(size_t)b * 64 + s * 32 + g * 8 + 4]) = o1;
        }
    }
    float lv = (lane < F_N) ? lrbuf[wid][lane] : 0.f;
    #pragma unroll
    for (int off = 32; off; off >>= 1) lv += __shfl_xor(lv, off);
    if (lane == 0) ws_lr[b] = lv;
}

// ---------------- MLP head: 8 samples per block ----------------
__global__ __launch_bounds__(256, 4) void anfm_mlp_kernel(
    const float* __restrict__ ws_afm, const float* __restrict__ ws_lr,
    const float* __restrict__ w0, const float* __restrict__ b0,
    const float* __restrict__ w1, const float* __restrict__ b1,
    const float* __restrict__ w2, const float* __restrict__ b2,
    const float* __restrict__ bias, float* __restrict__ out)
{
    __shared__ float afm_t[8][64];
    __shared__ float h0t[8][256];
    const int tid  = threadIdx.x;
    const int lane = tid & 63;
    const int w    = tid >> 6;
    const int blk  = blockIdx.x;
    const int s0   = w * 2;    // this wave's first local sample

    for (int it = tid; it < 8 * 64; it += 256) {
        int s = it >> 6, e = it & 63;
        afm_t[s][e] = ws_afm[((size_t)blk * 8 + s) * 64 + e];
    }
    __syncthreads();

    // L0: 64 -> 256
    float acc0[2][4];
    float bb0[4];
    #pragma unroll
    for (int q = 0; q < 4; q++) bb0[q] = b0[lane + 64 * q];
    #pragma unroll
    for (int s = 0; s < 2; s++)
        #pragma unroll
        for (int q = 0; q < 4; q++) acc0[s][q] = bb0[q];
    for (int e = 0; e < 64; e += 4) {
        floatx4 a[2];
        #pragma unroll
        for (int s = 0; s < 2; s++)
            a[s] = *reinterpret_cast<const floatx4*>(&afm_t[s0 + s][e]);
        #pragma unroll
        for (int k = 0; k < 4; k++) {
            float wv[4];
            #pragma unroll
            for (int q = 0; q < 4; q++) wv[q] = w0[(e + k) * 256 + lane + 64 * q];
            #pragma unroll
            for (int s = 0; s < 2; s++)
                #pragma unroll
                for (int q = 0; q < 4; q++)
                    acc0[s][q] = fmaf(a[s][k], wv[q], acc0[s][q]);
        }
    }
    #pragma unroll
    for (int s = 0; s < 2; s++)
        #pragma unroll
        for (int q = 0; q < 4; q++)
            h0t[s0 + s][lane + 64 * q] = fmaxf(acc0[s][q], 0.f);
    __syncthreads();

    // L1: 256 -> 128
    float acc1[2][2];
    float bb1[2];
    #pragma unroll
    for (int q = 0; q < 2; q++) bb1[q] = b1[lane + 64 * q];
    #pragma unroll
    for (int s = 0; s < 2; s++)
        #pragma unroll
        for (int q = 0; q < 2; q++) acc1[s][q] = bb1[q];
    for (int e = 0; e < 256; e += 4) {
        floatx4 h[2];
        #pragma unroll
        for (int s = 0; s < 2; s++)
            h[s] = *reinterpret_cast<const floatx4*>(&h0t[s0 + s][e]);
        #pragma unroll
        for (int k = 0; k < 4; k++) {
            float wv[2];
            #pragma unroll
            for (int q = 0; q < 2; q++) wv[q] = w1[(e + k) * 128 + lane + 64 * q];
            #pragma unroll
            for (int s = 0; s < 2; s++)
                #pragma unroll
                for (int q = 0; q < 2; q++)
                    acc1[s][q] = fmaf(h[s][k], wv[q], acc1[s][q]);
        }
    }

    // L2: 128 -> 1, + lr + bias
    float w2a = w2[lane], w2b = w2[lane + 64];
    float base = b2[0] + bias[0];
    #pragma unroll
    for (int s = 0; s < 2; s++) {
        float part = fmaxf(acc1[s][0], 0.f) * w2a + fmaxf(acc1[s][1], 0.f) * w2b;
        #pragma unroll
        for (int off = 32; off; off >>= 1) part += __shfl_xor(part, off);
        if (lane == 0) {
            int sg = blk * 8 + s0 + s;
            out[sg] = part + base + ws_lr[sg];
        }
    }
}

extern "C" void kernel_launch(void* const* d_in, const int* in_sizes, int n_in,
                              void* d_out, int out_size, void* d_ws, size_t ws_size,
                              hipStream_t stream) {
    const int*   x_idx   = (const int*)d_in[0];
    const float* embed_w = (const float*)d_in[1];
    const float* embed_b = (const float*)d_in[2];
    const float* att_w   = (const float*)d_in[3];
    const float* att_b   = (const float*)d_in[4];
    const float* att_p   = (const float*)d_in[5];
    const float* w0      = (const float*)d_in[6];
    const float* b0      = (const float*)d_in[7];
    const float* w1      = (const float*)d_in[8];
    const float* b1      = (const float*)d_in[9];
    const float* w2      = (const float*)d_in[10];
    const float* b2      = (const float*)d_in[11];
    const float* bias    = (const float*)d_in[12];

    // ws layout: afm [B,64] f32 | lr [B] f32
    float* ws_afm = (float*)d_ws;
    float* ws_lr  = ws_afm + (size_t)B_N * E_N;
    float* out    = (float*)d_out;

    anfm_attn_kernel<<<B_N / 4, 256, 0, stream>>>(x_idx, embed_w, embed_b,
                                                  att_w, att_b, att_p,
                                                  ws_afm, ws_lr);
    anfm_mlp_kernel<<<B_N / 8, 256, 0, stream>>>(ws_afm, ws_lr,
                                                 w0, b0, w1, b1, w2, b2, bias, out);
}